// Round 8
// baseline (823.585 us; speedup 1.0000x reference)
//
#include <hip/hip_runtime.h>
#include <cstdint>
#include <cstddef>

// B=2, S=2048, E=1024, H=16, HD=64; rows = 4096; heads = 32.
//
// Precision tiers (validated r7, absmax 0.0156 vs 0.042 threshold):
//  - Q/K projections + QK^T: bf16 hi/lo split, 3 chunks.
//  - V projection, PV, out-GEMM: single bf16 chunk.
// r8: attn K/V double-buffered staging, per-sub softmax, launch fusion.
// r9: attn it-pairing (const 36 tiles/CU); NT attn stores.
// r10: Q/K normalize+head-gather fused into projection GEMM epilogue.
// r14: gemm_out64 (2 blocks/CU out-GEMM). r15: zero-fill moved to tails
//  of earlier kernels (neutral but keeps attn's barrier path clean).
// r16: attn pass-2 store-drain fix, two coordinated changes:
//  (a) V staged from LDS -> read DIRECT from global Vt (L2-resident,
//      ~1MB/XCD). V loads issued early (post-prefetch, pre-stores), so
//      PV's compiler-inserted vmcnt wait retires prefetch+V but NOT the
//      4 newer nt stores. Removes vt LDS (16KB) + 1 gload/jt.
//  (b) pass-2 barriers: s_waitcnt vmcnt(4) + raw s_barrier for waves that
//      stored last iter (lets the 4 nt stores float a full phase instead
//      of being drained at HBM latency ~900cy by __syncthreads' vmcnt(0));
//      vmcnt(0) for waves that didn't store (masked / jt==0) — fixes the
//      masked-wave race r13 had. NO sched_barrier fences (r13's regression
//      mechanism, m141-class). Correctness is compiler-order-robust:
//      consuming any V load force-retires the older prefetch loads.

typedef __bf16 bf16x4 __attribute__((ext_vector_type(4)));
typedef __bf16 bf16x8 __attribute__((ext_vector_type(8)));
typedef float floatx4 __attribute__((ext_vector_type(4)));

#define GLOAD_LDS16(g, l)                                                      \
    __builtin_amdgcn_global_load_lds(                                          \
        (const __attribute__((address_space(1))) void*)(g),                    \
        (__attribute__((address_space(3))) void*)(l), 16, 0, 0)

__device__ __forceinline__ void nt_store4(float* p, floatx4 v) {
    __builtin_nontemporal_store(v, (floatx4*)p);
}

// zero one fill-unit: u = head*128 + rg; rows [rg*16, rg*16+16),
// cols [(((r0+15)>>6)+1)*64, 2048) — exactly the tiles attn_mfma skips.
__device__ __forceinline__ void fill_unit(float* __restrict__ Attn,
                                          int u, int tid) {
    const int head = u >> 7, rg = u & 127;
    const int r0 = rg * 16;
    const int c0 = (((r0 + 15) >> 6) + 1) * 64;
    if (c0 >= 2048) return;
    float* base = Attn + (size_t)head * (2048ull * 2048) + (size_t)r0 * 2048 + c0;
    const int w = 2048 - c0;
    floatx4 z4 = (floatx4){0.f, 0.f, 0.f, 0.f};
    #pragma unroll 4
    for (int rowi = 0; rowi < 16; ++rowi) {
        float* rp = base + (size_t)rowi * 2048;
        for (int c = tid * 4; c < w; c += 1024)
            nt_store4(rp + c, z4);
    }
}

// ------------------------------------------------------------------
// prep: fused input preprocessing.
//  blocks [0, 12288): split_a — X fp32 -> Ap bf16 [hi|lo] rows (z = b/4096)
//    (z==2 writes hi only: V projection is single-chunk)
//  blocks [12288, 12288+256*nW): split_bt — W fp32 -> Bp bf16 [hi|lo] cols
// ------------------------------------------------------------------
__global__ __launch_bounds__(256) void prep(
    const float* __restrict__ x0, const float* __restrict__ x1,
    const float* __restrict__ x2, __bf16* __restrict__ ApBase,
    const float* __restrict__ w0, const float* __restrict__ w1,
    const float* __restrict__ w2, const float* __restrict__ w3,
    __bf16* __restrict__ Bp0, __bf16* __restrict__ BpzDst, int nW)
{
    const int flat = (int)blockIdx.x;
    const int tid = (int)threadIdx.x;

    if (flat < 12288) {
        const int z = flat >> 12;            // /4096
        const int bx = flat & 4095;
        const float* X = z == 0 ? x0 : (z == 1 ? x1 : x2);
        __bf16* Ap = ApBase + (size_t)z * (4096ull * 2048);
        const int idx = bx * 256 + tid;
        const int r = idx >> 8;
        const int c = (idx & 255) * 4;
        float4 t = *(const float4*)(X + (size_t)r * 1024 + c);
        bf16x4 hi, lo;
        hi[0] = (__bf16)t.x; lo[0] = (__bf16)(t.x - (float)hi[0]);
        hi[1] = (__bf16)t.y; lo[1] = (__bf16)(t.y - (float)hi[1]);
        hi[2] = (__bf16)t.z; lo[2] = (__bf16)(t.z - (float)hi[2]);
        hi[3] = (__bf16)t.w; lo[3] = (__bf16)(t.w - (float)hi[3]);
        *(bf16x4*)(Ap + (size_t)r * 2048 + c) = hi;
        if (z != 2)
            *(bf16x4*)(Ap + (size_t)r * 2048 + 1024 + c) = lo;
        return;
    }

    const int t = flat - 12288;
    const int slice = t >> 8;
    if (slice >= nW) return;
    const int idx = t & 255;
    const float* W = slice == 0 ? w0 : (slice == 1 ? w1 : (slice == 2 ? w2 : w3));
    __bf16* Bp = slice < 3 ? (Bp0 + (size_t)slice * (1024ull * 2048)) : BpzDst;

    __shared__ float tile[64][65];
    const int k0 = (idx >> 4) * 64, n0 = (idx & 15) * 64;
    #pragma unroll
    for (int p = 0; p < 4; ++p) {
        int kr = p * 16 + (tid >> 4);
        float4 v = *(const float4*)(W + (size_t)(k0 + kr) * 1024 + n0 + (tid & 15) * 4);
        tile[kr][(tid & 15) * 4 + 0] = v.x; tile[kr][(tid & 15) * 4 + 1] = v.y;
        tile[kr][(tid & 15) * 4 + 2] = v.z; tile[kr][(tid & 15) * 4 + 3] = v.w;
    }
    __syncthreads();
    const int nr = tid >> 2, kc = (tid & 3) * 16;
    bf16x8 hi0, hi1, lo0, lo1;
    #pragma unroll
    for (int j = 0; j < 8; ++j) {
        float x = tile[kc + j][nr];
        __bf16 h = (__bf16)x; hi0[j] = h; lo0[j] = (__bf16)(x - (float)h);
        float y = tile[kc + 8 + j][nr];
        __bf16 g = (__bf16)y; hi1[j] = g; lo1[j] = (__bf16)(y - (float)g);
    }
    __bf16* row = Bp + (size_t)(n0 + nr) * 2048;
    *(bf16x8*)(row + k0 + kc)            = hi0;
    *(bf16x8*)(row + k0 + kc + 8)        = hi1;
    *(bf16x8*)(row + 1024 + k0 + kc)     = lo0;
    *(bf16x8*)(row + 1024 + k0 + kc + 8) = lo1;
}

// standalone Wz split for small-ws fallback (writes d_in[4] after prep)
__global__ __launch_bounds__(256) void split_bt1(
    const float* __restrict__ W, __bf16* __restrict__ Bp)
{
    __shared__ float tile[64][65];
    const int tid = (int)threadIdx.x;
    const int k0 = blockIdx.y * 64, n0 = blockIdx.x * 64;
    #pragma unroll
    for (int p = 0; p < 4; ++p) {
        int kr = p * 16 + (tid >> 4);
        float4 v = *(const float4*)(W + (size_t)(k0 + kr) * 1024 + n0 + (tid & 15) * 4);
        tile[kr][(tid & 15) * 4 + 0] = v.x; tile[kr][(tid & 15) * 4 + 1] = v.y;
        tile[kr][(tid & 15) * 4 + 2] = v.z; tile[kr][(tid & 15) * 4 + 3] = v.w;
    }
    __syncthreads();
    const int nr = tid >> 2, kc = (tid & 3) * 16;
    bf16x8 hi0, hi1, lo0, lo1;
    #pragma unroll
    for (int j = 0; j < 8; ++j) {
        float x = tile[kc + j][nr];
        __bf16 h = (__bf16)x; hi0[j] = h; lo0[j] = (__bf16)(x - (float)h);
        float y = tile[kc + 8 + j][nr];
        __bf16 g = (__bf16)y; hi1[j] = g; lo1[j] = (__bf16)(y - (float)g);
    }
    __bf16* row = Bp + (size_t)(n0 + nr) * 2048;
    *(bf16x8*)(row + k0 + kc)            = hi0;
    *(bf16x8*)(row + k0 + kc + 8)        = hi1;
    *(bf16x8*)(row + 1024 + k0 + kc)     = lo0;
    *(bf16x8*)(row + 1024 + k0 + kc + 8) = lo1;
}

// ------------------------------------------------------------------
// gemm_split: projections. Grid (n:8, m:32, z:3).
// fuseQK: z in {0,1} remapped M-blocking + normalize/gather -> Qp/Kp;
// z==2 transposeOut -> PTv. Tail: fill-units 640..4095 (attn heads 5..31).
// ------------------------------------------------------------------
__global__ __launch_bounds__(256) void gemm_split(
    const __bf16* __restrict__ Ap0, size_t aSlice, int aStride,
    const __bf16* __restrict__ Bp0, size_t bSlice,
    const float* __restrict__ b0, const float* __restrict__ b1,
    const float* __restrict__ b2, float* __restrict__ PTv,
    int chunksQK, int chunksV,
    __bf16* __restrict__ Qp, __bf16* __restrict__ Kp,
    float* __restrict__ AttnFill)
{
    const int z = blockIdx.z;
    const int nch = (z == 2) ? chunksV : chunksQK;
    const bool fuse = (z < 2);
    const __bf16* Ap = Ap0 + (size_t)z * aSlice;
    const __bf16* Bp = Bp0 + (size_t)z * bSlice;
    const float* bias = z == 0 ? b0 : (z == 1 ? b1 : b2);

    __shared__ __bf16 As[2 * 128 * 32];
    __shared__ __bf16 Bs[2 * 128 * 32];

    const int tid = (int)threadIdx.x;
    const int wave = tid >> 6, lane = tid & 63;
    const int quad = lane >> 4, tl = lane & 15;
    const int m0 = blockIdx.y * 128, n0 = blockIdx.x * 128;
    const int waveM = wave >> 1, waveN = wave & 1;

    floatx4 acc[4][4];
    #pragma unroll
    for (int i = 0; i < 4; ++i)
        #pragma unroll
        for (int j = 0; j < 4; ++j)
            acc[i][j] = (floatx4){0.f, 0.f, 0.f, 0.f};

    const int sRow  = (wave << 4) + (lane >> 2);
    const int sColB = (lane & 3) << 4;
    auto* AsL = (__attribute__((address_space(3))) char*)As;
    auto* BsL = (__attribute__((address_space(3))) char*)Bs;
    const int ldsOff = wave * 1024;

    // A global row for tile-row mrow (identity, or remapped for fused Q/K:
    // m = g'*64+u -> r = (u>>5)*2048 + by*64 + g'*32 + (u&31))
    size_t aRow[2];
    #pragma unroll
    for (int i = 0; i < 2; ++i) {
        const int mrow = i * 64 + sRow;
        if (fuse) {
            const int u = mrow & 63;
            aRow[i] = (size_t)((u >> 5) * 2048 + (m0 >> 1) + (mrow >> 6) * 32 + (u & 31));
        } else {
            aRow[i] = (size_t)(m0 + mrow);
        }
    }

    for (int k0 = 0; k0 < 1024; k0 += 32) {
        __syncthreads();
        #pragma unroll
        for (int i = 0; i < 2; ++i) {
            GLOAD_LDS16((const char*)(Ap + aRow[i] * aStride + k0) + sColB,
                        AsL + i * 4096 + ldsOff);
            GLOAD_LDS16((const char*)(Bp + (size_t)(n0 + i*64 + sRow) * 2048 + k0) + sColB,
                        BsL + i * 4096 + ldsOff);
            if (nch > 1) {
                GLOAD_LDS16((const char*)(Ap + 1024 + aRow[i] * aStride + k0) + sColB,
                            AsL + 8192 + i * 4096 + ldsOff);
                GLOAD_LDS16((const char*)(Bp + 1024 + (size_t)(n0 + i*64 + sRow) * 2048 + k0) + sColB,
                            BsL + 8192 + i * 4096 + ldsOff);
            }
        }
        __syncthreads();

        bf16x8 ah[4], bh[4], al[4], bl[4];
        #pragma unroll
        for (int mt = 0; mt < 4; ++mt)
            ah[mt] = *(const bf16x8*)(As + (waveM*64 + mt*16 + tl) * 32 + quad * 8);
        #pragma unroll
        for (int nt = 0; nt < 4; ++nt)
            bh[nt] = *(const bf16x8*)(Bs + (waveN*64 + nt*16 + tl) * 32 + quad * 8);
        #pragma unroll
        for (int mt = 0; mt < 4; ++mt)
            #pragma unroll
            for (int nt = 0; nt < 4; ++nt)
                acc[mt][nt] = __builtin_amdgcn_mfma_f32_16x16x32_bf16(
                    ah[mt], bh[nt], acc[mt][nt], 0, 0, 0);
        if (nch > 1) {
            #pragma unroll
            for (int mt = 0; mt < 4; ++mt)
                al[mt] = *(const bf16x8*)(As + 4096 + (waveM*64 + mt*16 + tl) * 32 + quad * 8);
            #pragma unroll
            for (int mt = 0; mt < 4; ++mt)
                #pragma unroll
                for (int nt = 0; nt < 4; ++nt)
                    acc[mt][nt] = __builtin_amdgcn_mfma_f32_16x16x32_bf16(
                        al[mt], bh[nt], acc[mt][nt], 0, 0, 0);
        }
        if (nch > 2) {
            #pragma unroll
            for (int nt = 0; nt < 4; ++nt)
                bl[nt] = *(const bf16x8*)(Bs + 4096 + (waveN*64 + nt*16 + tl) * 32 + quad * 8);
            #pragma unroll
            for (int mt = 0; mt < 4; ++mt)
                #pragma unroll
                for (int nt = 0; nt < 4; ++nt)
                    acc[mt][nt] = __builtin_amdgcn_mfma_f32_16x16x32_bf16(
                        ah[mt], bl[nt], acc[mt][nt], 0, 0, 0);
        }
    }

    if (fuse) {
        // normalize + head-gather epilogue. Group = 64 elements (fixed e,
        // u in [0,64)) all held by waves with this waveM.
        __bf16* Outp = (z == 0) ? Qp : Kp;
        const int g = ((m0 >> 7) << 1) + waveM;       // sp & 63
        #pragma unroll
        for (int nt = 0; nt < 4; ++nt) {
            const int e = n0 + waveN * 64 + nt * 16 + tl;
            const float bb = bias[e];
            float vals[16];
            float ss = 0.f;
            #pragma unroll
            for (int mt = 0; mt < 4; ++mt)
                #pragma unroll
                for (int reg = 0; reg < 4; ++reg) {
                    float vv = acc[mt][nt][reg] + bb;
                    vals[mt * 4 + reg] = vv;
                    ss += vv * vv;
                }
            ss += __shfl_xor(ss, 16);
            ss += __shfl_xor(ss, 32);
            const float inv = 1.0f / sqrtf(ss);
            const int head = ((e >> 9) << 4) + ((e >> 5) & 15);
            const int sp = ((e & 31) << 6) + g;
            __bf16* row = Outp + ((size_t)head * 2048 + sp) * 128;
            // d quadruple (d0..d0+3) <- vals{(mt,r0),(mt+2,r0),(mt,r0+1),
            // (mt+2,r0+1)}: bf16x4 8B stores (value-identical to scalars).
            #pragma unroll
            for (int mt = 0; mt < 2; ++mt)
                #pragma unroll
                for (int r0 = 0; r0 < 4; r0 += 2) {
                    const int d0 = (mt * 16 + quad * 4 + r0) * 2;
                    float v0 = vals[mt * 4 + r0] * inv;
                    float v1 = vals[(mt + 2) * 4 + r0] * inv;
                    float v2 = vals[mt * 4 + r0 + 1] * inv;
                    float v3 = vals[(mt + 2) * 4 + r0 + 1] * inv;
                    bf16x4 hv, lo4;
                    hv[0] = (__bf16)v0; lo4[0] = (__bf16)(v0 - (float)hv[0]);
                    hv[1] = (__bf16)v1; lo4[1] = (__bf16)(v1 - (float)hv[1]);
                    hv[2] = (__bf16)v2; lo4[2] = (__bf16)(v2 - (float)hv[2]);
                    hv[3] = (__bf16)v3; lo4[3] = (__bf16)(v3 - (float)hv[3]);
                    *(bf16x4*)(row + d0) = hv;
                    *(bf16x4*)(row + 64 + d0) = lo4;
                }
        }
    } else {
        // transposed PT output for v_transpose (z==2)
        #pragma unroll
        for (int nt = 0; nt < 4; ++nt) {
            const int e = n0 + waveN * 64 + nt * 16 + tl;
            const float bb = bias[e];
            #pragma unroll
            for (int mt = 0; mt < 4; ++mt) {
                floatx4 v = acc[mt][nt] + bb;
                *(floatx4*)(PTv + (size_t)e * 4096 + m0 + waveM * 64 + mt * 16 + quad * 4) = v;
            }
        }
    }

    // tail: attn upper-triangle zero-fill, heads 5..31 (units 640..4095).
    {
        const int L = (int)blockIdx.x + (int)blockIdx.y * 8 + z * 256; // 0..767
        for (int u = 640 + L; u < 4096; u += 768)
            fill_unit(AttnFill, u, tid);
    }
}

// ------------------------------------------------------------------
// gemm_out64 (r14): out-GEMM, 64x128 tiles, grid (8,64) = 2 blocks/CU.
// Tail: fill-units 0..127 (attn head 0; PTv dead, attn already done).
// ------------------------------------------------------------------
__global__ __launch_bounds__(256) void gemm_out64(
    const __bf16* __restrict__ Ap, const __bf16* __restrict__ Bp,
    const float* __restrict__ bias, float* __restrict__ Out,
    float* __restrict__ AttnFill)
{
    __shared__ __bf16 As[64 * 32];
    __shared__ __bf16 Bs[128 * 32];

    const int tid = (int)threadIdx.x;
    const int wave = tid >> 6, lane = tid & 63;
    const int quad = lane >> 4, tl = lane & 15;
    const int m0 = blockIdx.y * 64, n0 = blockIdx.x * 128;
    const int wm = wave >> 1, wn = wave & 1;

    floatx4 acc[2][4];
    #pragma unroll
    for (int i = 0; i < 2; ++i)
        #pragma unroll
        for (int j = 0; j < 4; ++j)
            acc[i][j] = (floatx4){0.f, 0.f, 0.f, 0.f};

    const int sRow  = (wave << 4) + (lane >> 2);   // 0..63
    const int sColB = (lane & 3) << 4;
    auto* AsL = (__attribute__((address_space(3))) char*)As;
    auto* BsL = (__attribute__((address_space(3))) char*)Bs;
    const int ldsOff = wave * 1024;

    for (int k0 = 0; k0 < 1024; k0 += 32) {
        __syncthreads();
        GLOAD_LDS16((const char*)(Ap + (size_t)(m0 + sRow) * 1024 + k0) + sColB,
                    AsL + ldsOff);
        #pragma unroll
        for (int i = 0; i < 2; ++i)
            GLOAD_LDS16((const char*)(Bp + (size_t)(n0 + i*64 + sRow) * 2048 + k0) + sColB,
                        BsL + i * 4096 + ldsOff);
        __syncthreads();

        bf16x8 ah[2], bh[4];
        #pragma unroll
        for (int mt = 0; mt < 2; ++mt)
            ah[mt] = *(const bf16x8*)(As + (wm*32 + mt*16 + tl) * 32 + quad * 8);
        #pragma unroll
        for (int nt = 0; nt < 4; ++nt)
            bh[nt] = *(const bf16x8*)(Bs + (wn*64 + nt*16 + tl) * 32 + quad * 8);
        #pragma unroll
        for (int mt = 0; mt < 2; ++mt)
            #pragma unroll
            for (int nt = 0; nt < 4; ++nt)
                acc[mt][nt] = __builtin_amdgcn_mfma_f32_16x16x32_bf16(
                    ah[mt], bh[nt], acc[mt][nt], 0, 0, 0);
    }

    #pragma unroll
    for (int mt = 0; mt < 2; ++mt) {
        const int rbase = m0 + wm * 32 + mt * 16 + quad * 4;
        #pragma unroll
        for (int nt = 0; nt < 4; ++nt) {
            const int e = n0 + wn * 64 + nt * 16 + tl;
            const float bb = bias[e];
            #pragma unroll
            for (int reg = 0; reg < 4; ++reg)
                Out[(size_t)(rbase + reg) * 1024 + e] = acc[mt][nt][reg] + bb;
        }
    }

    const int L = (int)blockIdx.x + (int)blockIdx.y * 8;   // 0..511
    if (L < 128)
        fill_unit(AttnFill, L, tid);
}

// ------------------------------------------------------------------
// v_transpose: PTv[e][4096] -> Vt[head][d=64][2048] bf16 (hi only).
// Tail: fill-units 128..639 (attn heads 1..4; Ap/Bp dead by now).
// ------------------------------------------------------------------
__global__ __launch_bounds__(256) void v_transpose(
    const float* __restrict__ PTv, __bf16* __restrict__ Vt,
    float* __restrict__ AttnFill)
{
    const int t = (int)blockIdx.x;        // 0..1023
    const int tid = (int)threadIdx.x;
    const int st = t & 31, head = t >> 5;
    const int c = (head >> 4) * 512 + (head & 15) * 32 + st;
    const float* __restrict__ row = PTv + (size_t)c * 4096;

    __shared__ float tile[64][65];
    #pragma unroll
    for (int i = 0; i < 4; ++i) {
        int o = i * 1024 + tid * 4;
        float4 v4 = *(const float4*)(row + o);
        float vals[4] = {v4.x, v4.y, v4.z, v4.w};
        #pragma unroll
        for (int e = 0; e < 4; ++e) {
            int oo = o + e;
            int d  = ((oo & 2047) & 31) * 2 + (oo >> 11);
            int sl = (oo & 2047) >> 5;
            tile[sl][d] = vals[e];
        }
    }
    __syncthreads();

    const int d = tid >> 2, jb = (tid & 3) * 16;
    bf16x8 h0, h1;
    #pragma unroll
    for (int j = 0; j < 8; ++j) {
        h0[j] = (__bf16)tile[jb + j][d];
        h1[j] = (__bf16)tile[jb + 8 + j][d];
    }
    size_t bh = ((size_t)head * 64 + d) * 2048 + st * 64 + jb;
    *(bf16x8*)(Vt + bh)     = h0;
    *(bf16x8*)(Vt + bh + 8) = h1;

    if (t < 512)
        fill_unit(AttnFill, 128 + t, tid);
}

// ------------------------------------------------------------------
// attn_mfma: block = (128 i-rows, head); 8 waves x 16 rows, 512 threads.
// QK^T: 3-chunk hi/lo. PV: single chunk, V read DIRECT from global Vt
// (r16 — no LDS staging). K staged via global_load_lds (XOR chunk
// swizzle), double-buffered. it-pairing: CU's two resident blocks sum to
// a constant 36 j-tiles; nt stores. Pass-2 barriers: counted vmcnt(4)
// (stores float a full phase), vmcnt(0) for waves that didn't store.
// ------------------------------------------------------------------
__global__ __launch_bounds__(512, 4) void attn_mfma(
    const __bf16* __restrict__ Qp, const __bf16* __restrict__ Kp,
    const __bf16* __restrict__ Vt, float* __restrict__ Attn,
    __bf16* __restrict__ Az)
{
    const int flat = (int)blockIdx.x;
    const int head = flat & 31;
    const int idx  = flat >> 5;                    // 0..15
    // pair heavy+light: CU gets blocks flat and flat+256 -> it and 15-it.
    const int it   = (idx < 8) ? (15 - idx) : (idx - 8);
    const int tid = (int)threadIdx.x;
    const int w = tid >> 6, lane = tid & 63;
    const int quad = lane >> 4, tl = lane & 15;
    const int t7 = tl & 7;
    const int i0 = it * 128;
    const int jtmax = 2 * it + 1;                  // always odd
    const int wrowMax = i0 + w * 16 + 15;
    const int wdiag   = (i0 + w * 16) >> 6;
    const int irowBase = w * 16 + quad * 4;

    const __bf16* __restrict__ Qh = Qp + ((size_t)head * 2048 + i0) * 128;
    const __bf16* __restrict__ Kh = Kp + (size_t)head * 2048 * 128;
    const __bf16* __restrict__ Vh = Vt + (size_t)head * 64 * 2048;
    float* __restrict__ Ah = Attn + (size_t)head * ((size_t)2048 * 2048);

    __shared__ __bf16 kb[2][64 * 128];   // K tile dbuf (2 x 16 KB)
    __shared__ __bf16 ps[8][16 * 72];    // wave-private P staging (18 KB)
    __bf16* psw = ps[w];
    auto* kbL = (__attribute__((address_space(3))) char*)&kb[0][0];

    // per-lane staging sources (swizzled)
    const char* kSrc[2];
    #pragma unroll
    for (int i = 0; i < 2; ++i) {
        int d  = i * 512 + tid;
        int rK = d >> 4, cK = (d & 15) ^ (rK & 7);
        kSrc[i] = (const char*)(Kh + (size_t)rK * 128) + cK * 16;
    }
    const int ok0 = ((quad)      ^ t7) * 8;
    const int ok1 = ((quad + 4)  ^ t7) * 8;
    const int ok2 = ((quad + 8)  ^ t7) * 8;
    const int ok3 = ((quad + 12) ^ t7) * 8;

    // Q fragments direct from global (once per block)
    const __bf16* qrow = Qh + (size_t)(w * 16 + tl) * 128;
    bf16x8 qhi0 = *(const bf16x8*)(qrow + quad * 8);
    bf16x8 qhi1 = *(const bf16x8*)(qrow + 32 + quad * 8);
    bf16x8 qlo0 = *(const bf16x8*)(qrow + 64 + quad * 8);
    bf16x8 qlo1 = *(const bf16x8*)(qrow + 96 + quad * 8);

    float m[4], l[4];
    #pragma unroll
    for (int r = 0; r < 4; ++r) { m[r] = -3.0e38f; l[r] = 0.0f; }

    // ---------- pass 1: stats (K dbuf) ----------
    #pragma unroll
    for (int i = 0; i < 2; ++i)                       // prologue: jt=0 -> kb[0]
        GLOAD_LDS16(kSrc[i], kbL + i * 8192 + w * 1024);

    for (int jt = 0; jt <= jtmax; ++jt) {
        const int cur = jt & 1;
        __syncthreads();                              // publishes kb[cur]
        if (jt < jtmax) {                             // issue jt+1 -> kb[cur^1]
            #pragma unroll
            for (int i = 0; i < 2; ++i)
                GLOAD_LDS16(kSrc[i] + (size_t)(jt + 1) * 16384,
                            kbL + (cur ^ 1) * 16384 + i * 8192 + w * 1024);
        }
        if (jt * 64 > wrowMax) continue;              // fully masked (wave-uniform)

        const __bf16* kbuf = &kb[cur][0];
        const bool diag = (jt == wdiag);
        #pragma unroll
        for (int sub = 0; sub < 4; ++sub) {
            const __bf16* kr = kbuf + (sub * 16 + tl) * 128;
            bf16x8 khi0 = *(const bf16x8*)(kr + ok0);
            bf16x8 khi1 = *(const bf16x8*)(kr + ok1);
            bf16x8 klo0 = *(const bf16x8*)(kr + ok2);
            bf16x8 klo1 = *(const bf16x8*)(kr + ok3);
            floatx4 s = (floatx4){0.f, 0.f, 0.f, 0.f};
            s = __builtin_amdgcn_mfma_f32_16x16x32_bf16(qhi0, khi0, s, 0, 0, 0);
            s = __builtin_amdgcn_mfma_f32_16x16x32_bf16(qhi1, khi1, s, 0, 0, 0);
            s = __builtin_amdgcn_mfma_f32_16x16x32_bf16(qhi0, klo0, s, 0, 0, 0);
            s = __builtin_amdgcn_mfma_f32_16x16x32_bf16(qhi1, klo1, s, 0, 0, 0);
            s = __builtin_amdgcn_mfma_f32_16x16x32_bf16(qlo0, khi0, s, 0, 0, 0);
            s = __builtin_amdgcn_mfma_f32_16x16x32_bf16(qlo1, khi1, s, 0, 0, 0);
            const int col = jt * 64 + sub * 16 + tl;
            #pragma unroll
            for (int reg = 0; reg < 4; ++reg) {
                float lv = s[reg] * 1000.0f;
                if (diag && (col > i0 + irowBase + reg)) lv = -1.0e9f;
                float mn = fmaxf(m[reg], lv);
                l[reg] = l[reg] * __expf(m[reg] - mn) + __expf(lv - mn);
                m[reg] = mn;
            }
        }
    }

    // reduce stats across the 16 tl lanes
    #pragma unroll
    for (int reg = 0; reg < 4; ++reg) {
        #pragma unroll
        for (int mk = 8; mk >= 1; mk >>= 1) {
            float mo = __shfl_xor(m[reg], mk);
            float lo = __shfl_xor(l[reg], mk);
            float mn = fmaxf(m[reg], mo);
            l[reg] = l[reg] * __expf(m[reg] - mn) + lo * __expf(mo - mn);
            m[reg] = mn;
        }
    }
    float inv_l[4];
    #pragma unroll
    for (int reg = 0; reg < 4; ++reg) inv_l[reg] = 1.0f / l[reg];

    // ---------- pass 2: attn write + PV (K dbuf; V direct from global) ----------
    floatx4 zacc[4];
    #pragma unroll
    for (int t = 0; t < 4; ++t) zacc[t] = (floatx4){0.f, 0.f, 0.f, 0.f};

    // prologue: jt=0 -> kb[0]. Safe: pass-1's last compute used
    // kb[jtmax&1] = kb[1] (jtmax odd), and all waves passed that barrier.
    #pragma unroll
    for (int i = 0; i < 2; ++i)
        GLOAD_LDS16(kSrc[i], kbL + i * 8192 + w * 1024);

    for (int jt = 0; jt <= jtmax; ++jt) {
        const int cur = jt & 1;
        // r16 counted-vmcnt barrier. If this wave stored last iteration,
        // its VMEM queue is [<=2 prefetch already retired by PV's V-wait]
        // [4 nt stores] -> vmcnt(4) passes without draining the stores.
        // Otherwise (jt==0 or previously masked) the queue holds only
        // prefetch loads -> vmcnt(0) so kb[cur] is complete before the
        // barrier publishes it. Wave-uniform branch (wrowMax is uniform).
        const bool prevStored = (jt > 0) && ((jt - 1) * 64 <= wrowMax);
        if (prevStored) {
            __asm__ volatile("s_waitcnt vmcnt(4)" ::: "memory");
        } else {
            __asm__ volatile("s_waitcnt vmcnt(0)" ::: "memory");
        }
        __builtin_amdgcn_s_barrier();                 // publishes kb[cur]

        if (jt < jtmax) {
            #pragma unroll
            for (int i = 0; i < 2; ++i)
                GLOAD_LDS16(kSrc[i] + (size_t)(jt + 1) * 16384,
                            kbL + (cur ^ 1) * 16384 + i * 8192 + w * 1024);
        }

        if (jt * 64 > wrowMax) continue;              // fully masked: pre-filled

        // V fragments for this tile, issued EARLY (before the nt stores)
        // so PV's compiler wait retires prefetch+V but not the stores.
        const __bf16* vg = Vh + (size_t)jt * 64;
        bf16x8 vhi[4][2];
        #pragma unroll
        for (int t = 0; t < 4; ++t) {
            const __bf16* vrow = vg + (size_t)(t * 16 + tl) * 2048;
            vhi[t][0] = *(const bf16x8*)(vrow + quad * 8);
            vhi[t][1] = *(const bf16x8*)(vrow + (quad + 4) * 8);
        }

        const __bf16* kbuf = &kb[cur][0];
        const bool diag = (jt == wdiag);
        #pragma unroll
        for (int sub = 0; sub < 4; ++sub) {
            const __bf16* kr = kbuf + (sub * 16 + tl) * 128;
            bf16x8 khi0 = *(const bf16x8*)(kr + ok0);
            bf16x8 khi1 = *(const bf16x8*)(kr + ok1);
            bf16x8 klo0 = *(const bf16x8*)(kr + ok2);
            bf16x8 klo1 = *(const bf16x8*)(kr + ok3);
            floatx4 s = (floatx4){0.f, 0.f, 0.f, 0.f};
            s = __builtin_amdgcn_mfma_f32_16x16x32_bf16(qhi0, khi0, s, 0, 0, 0);
            s = __builtin_amdgcn_mfma_f32_16x16x32_bf16(qhi1, khi1, s, 0, 0, 0);
            s = __builtin_amdgcn_mfma_f32_16x16x32_bf16(qhi0, klo0, s, 0, 0, 0);
            s = __builtin_amdgcn_mfma_f32_16x16x32_bf16(qhi1, klo1, s, 0, 0, 0);
            s = __builtin_amdgcn_mfma_f32_16x16x32_bf16(qlo0, khi0, s, 0, 0, 0);
            s = __builtin_amdgcn_mfma_f32_16x16x32_bf16(qlo1, khi1, s, 0, 0, 0);
            const int col = jt * 64 + sub * 16 + tl;
            #pragma unroll
            for (int reg = 0; reg < 4; ++reg) {
                float lv = s[reg] * 1000.0f;
                if (diag && (col > i0 + irowBase + reg)) lv = -1.0e9f;
                float p = __expf(lv - m[reg]) * inv_l[reg];
                psw[(quad * 4 + reg) * 72 + sub * 16 + tl] = (__bf16)p;
            }
        }
        // wave-private LDS: wait for writes (cross-lane reads next)
        __asm__ volatile("s_waitcnt lgkmcnt(0)" ::: "memory");

        // coalesced attn stores (non-temporal: never re-read on device)
        #pragma unroll
        for (int g = 0; g < 4; ++g) {
            bf16x4 pv = *(const bf16x4*)(psw + (g * 4 + quad) * 72 + tl * 4);
            floatx4 f = (floatx4){(float)pv[0], (float)pv[1],
                                  (float)pv[2], (float)pv[3]};
            nt_store4(Ah + (size_t)(i0 + w * 16 + g * 4 + quad) * 2048
                          + jt * 64 + tl * 4, f);
        }

        // P A-fragments, then PV MFMA (V hi only, from registers)
        bf16x8 p0 = *(const bf16x8*)(psw + tl * 72 + quad * 8);
        bf16x8 p1 = *(const bf16x8*)(psw + tl * 72 + 32 + quad * 8);
        #pragma unroll
        for (int t = 0; t < 4; ++t) {
            zacc[t] = __builtin_amdgcn_mfma_f32_16x16x32_bf16(p0, vhi[t][0], zacc[t], 0, 0, 0);
            zacc[t] = __builtin_amdgcn_mfma_f32_16x16x32_bf16(p1, vhi[t][1], zacc[t], 0, 0, 0);
        }
    }

    // epilogue: z -> Az bf16 (single chunk)
    const int b = head >> 4, h = head & 15;
    #pragma unroll
    for (int reg = 0; reg < 4; ++reg) {
        const size_t R = (size_t)b * 2048 + i0 + w * 16 + quad * 4 + reg;
        #pragma unroll
        for (int t = 0; t < 4; ++t)
            Az[R * 1024 + h * 64 + t * 16 + tl] = (__bf16)zacc[t][reg];
    }
}

// ------------------------------------------------------------------
extern "C" void kernel_launch(void* const* d_in, const int* in_sizes, int n_in,
                              void* d_out, int out_size, void* d_ws, size_t ws_size,
                              hipStream_t stream) {
    (void)in_sizes; (void)n_in; (void)out_size;
    const float* q  = (const float*)d_in[0];
    const float* k  = (const float*)d_in[1];
    const float* v  = (const float*)d_in[2];
    const float* Wq = (const float*)d_in[4];  const float* bq = (const float*)d_in[5];
    const float* Wk = (const float*)d_in[6];  const float* bk = (const float*)d_in[7];
    const float* Wv = (const float*)d_in[8];  const float* bv = (const float*)d_in[9];
    const float* Wz = (const float*)d_in[10]; const float* bz = (const float*)d_in[11];

    float* out0 = (float*)d_out;               // (2,2048,1024)
    float* attn = out0 + 4194304;              // (2,16,2048,2048) = 512 MB

    // Scratch in the attn region (head-aligned for fill safety):
    //  PTv: floats [0, 4194304)         = heads 0..1   (live until v_transpose)
    //  Ap0: floats [4194304, 16777216)  = heads 1..4   (live until proj done)
    //  Bp0: floats [16777216, 19922944) = heads 4..4.75
    float*  PTv = attn;
    __bf16* Ap0 = (__bf16*)(attn + 4194304);
    __bf16* Bp0 = (__bf16*)(attn + 16777216);

    // ws layout (big path): Qp 16MB | Kp 16MB | Vt 8MB | Az 8MB | Bpz 4MB
    __bf16 *Qp, *Kp, *Vtp, *Az, *Bpz;
    const bool bigWs = ws_size >= (size_t)54525952;   // 52 MB
    if (bigWs) {
        __bf16* ws = (__bf16*)d_ws;
        Qp = ws; Kp = ws + 8388608; Vtp = ws + 16777216; Az = ws + 20971520;
        Bpz = ws + 25165824;
    } else {
        Qp = (__bf16*)d_in[0]; Kp = (__bf16*)d_in[1]; Vtp = (__bf16*)d_in[2];
        Az = (__bf16*)d_ws;
        Bpz = (__bf16*)d_in[4];   // written by separate launch after prep
    }

    // prep: split_a (12288 blocks) + weight splits (256/slice)
    if (bigWs) {
        prep<<<dim3(12288 + 4 * 256), 256, 0, stream>>>(
            q, k, v, Ap0, Wq, Wk, Wv, Wz, Bp0, Bpz, 4);
    } else {
        prep<<<dim3(12288 + 3 * 256), 256, 0, stream>>>(
            q, k, v, Ap0, Wq, Wk, Wv, Wz, Bp0, nullptr, 3);
        split_bt1<<<dim3(16, 16), 256, 0, stream>>>(Wz, Bpz);
    }

    // projections: Q/K 3-chunk fused normalize+gather -> Qp/Kp;
    // V 1-chunk -> PTv. Tail-fills attn heads 5..31.
    gemm_split<<<dim3(8, 32, 3), 256, 0, stream>>>(
        Ap0, 4096ull*2048, 2048, Bp0, 1024ull*2048,
        bq, bk, bv, PTv, 3, 1,
        Qp, Kp, attn);

    // V transpose -> Vt. Tail-fills attn heads 1..4 (Ap/Bp dead).
    v_transpose<<<dim3(1024), 256, 0, stream>>>(PTv, Vtp, attn);

    attn_mfma<<<dim3(512), 512, 0, stream>>>(Qp, Kp, Vtp, attn, Az);

    // out-GEMM (2 blocks/CU). Tail-fills attn head 0 (PTv dead, attn done).
    gemm_out64<<<dim3(8, 64), 256, 0, stream>>>(Az, Bpz, bz, out0, attn);
}

// Round 9
// 804.240 us; speedup vs baseline: 1.0241x; 1.0241x over previous
//
#include <hip/hip_runtime.h>
#include <cstdint>
#include <cstddef>

// B=2, S=2048, E=1024, H=16, HD=64; rows = 4096; heads = 32.
//
// Precision tiers (validated r7, absmax 0.0156 vs 0.042 threshold):
//  - Q/K projections + QK^T: bf16 hi/lo split, 3 chunks.
//  - V projection, PV, out-GEMM: single bf16 chunk.
// r8: attn K/V double-buffered staging, per-sub softmax, launch fusion.
// r9: attn it-pairing (const 36 tiles/CU); NT attn stores.
// r10: Q/K normalize+head-gather fused into projection GEMM epilogue.
// r14: gemm_out64 (2 blocks/CU out-GEMM). r15: zero-fill moved to tails
//  of earlier kernels. Anchor measured 805.6/805.8 us (r14/r15).
// r16 (V direct-from-global + counted-vmcnt) REGRESSED +18us: each of the
//  8 waves re-loaded the full V tile from L2 (8x read amplification,
//  ~1GB extra L2 traffic ~ +28us predicted). REVERTED here.
// r17: byte-identical re-anchor of the r15 config (5th measurement of the
//  805-808 plateau). Theory family "pass-2 store-drain at barriers" is
//  falsified 5x (r12 plain stores, r13+r16 counted-vmcnt, r15 fill-move
//  neutral); no further single-variable lever clears the +-10-15us noise.

typedef __bf16 bf16x4 __attribute__((ext_vector_type(4)));
typedef __bf16 bf16x8 __attribute__((ext_vector_type(8)));
typedef float floatx4 __attribute__((ext_vector_type(4)));

#define GLOAD_LDS16(g, l)                                                      \
    __builtin_amdgcn_global_load_lds(                                          \
        (const __attribute__((address_space(1))) void*)(g),                    \
        (__attribute__((address_space(3))) void*)(l), 16, 0, 0)

__device__ __forceinline__ void nt_store4(float* p, floatx4 v) {
    __builtin_nontemporal_store(v, (floatx4*)p);
}

// zero one fill-unit: u = head*128 + rg; rows [rg*16, rg*16+16),
// cols [(((r0+15)>>6)+1)*64, 2048) — exactly the tiles attn_mfma skips.
__device__ __forceinline__ void fill_unit(float* __restrict__ Attn,
                                          int u, int tid) {
    const int head = u >> 7, rg = u & 127;
    const int r0 = rg * 16;
    const int c0 = (((r0 + 15) >> 6) + 1) * 64;
    if (c0 >= 2048) return;
    float* base = Attn + (size_t)head * (2048ull * 2048) + (size_t)r0 * 2048 + c0;
    const int w = 2048 - c0;
    floatx4 z4 = (floatx4){0.f, 0.f, 0.f, 0.f};
    #pragma unroll 4
    for (int rowi = 0; rowi < 16; ++rowi) {
        float* rp = base + (size_t)rowi * 2048;
        for (int c = tid * 4; c < w; c += 1024)
            nt_store4(rp + c, z4);
    }
}

// ------------------------------------------------------------------
// prep: fused input preprocessing.
//  blocks [0, 12288): split_a — X fp32 -> Ap bf16 [hi|lo] rows (z = b/4096)
//    (z==2 writes hi only: V projection is single-chunk)
//  blocks [12288, 12288+256*nW): split_bt — W fp32 -> Bp bf16 [hi|lo] cols
// ------------------------------------------------------------------
__global__ __launch_bounds__(256) void prep(
    const float* __restrict__ x0, const float* __restrict__ x1,
    const float* __restrict__ x2, __bf16* __restrict__ ApBase,
    const float* __restrict__ w0, const float* __restrict__ w1,
    const float* __restrict__ w2, const float* __restrict__ w3,
    __bf16* __restrict__ Bp0, __bf16* __restrict__ BpzDst, int nW)
{
    const int flat = (int)blockIdx.x;
    const int tid = (int)threadIdx.x;

    if (flat < 12288) {
        const int z = flat >> 12;            // /4096
        const int bx = flat & 4095;
        const float* X = z == 0 ? x0 : (z == 1 ? x1 : x2);
        __bf16* Ap = ApBase + (size_t)z * (4096ull * 2048);
        const int idx = bx * 256 + tid;
        const int r = idx >> 8;
        const int c = (idx & 255) * 4;
        float4 t = *(const float4*)(X + (size_t)r * 1024 + c);
        bf16x4 hi, lo;
        hi[0] = (__bf16)t.x; lo[0] = (__bf16)(t.x - (float)hi[0]);
        hi[1] = (__bf16)t.y; lo[1] = (__bf16)(t.y - (float)hi[1]);
        hi[2] = (__bf16)t.z; lo[2] = (__bf16)(t.z - (float)hi[2]);
        hi[3] = (__bf16)t.w; lo[3] = (__bf16)(t.w - (float)hi[3]);
        *(bf16x4*)(Ap + (size_t)r * 2048 + c) = hi;
        if (z != 2)
            *(bf16x4*)(Ap + (size_t)r * 2048 + 1024 + c) = lo;
        return;
    }

    const int t = flat - 12288;
    const int slice = t >> 8;
    if (slice >= nW) return;
    const int idx = t & 255;
    const float* W = slice == 0 ? w0 : (slice == 1 ? w1 : (slice == 2 ? w2 : w3));
    __bf16* Bp = slice < 3 ? (Bp0 + (size_t)slice * (1024ull * 2048)) : BpzDst;

    __shared__ float tile[64][65];
    const int k0 = (idx >> 4) * 64, n0 = (idx & 15) * 64;
    #pragma unroll
    for (int p = 0; p < 4; ++p) {
        int kr = p * 16 + (tid >> 4);
        float4 v = *(const float4*)(W + (size_t)(k0 + kr) * 1024 + n0 + (tid & 15) * 4);
        tile[kr][(tid & 15) * 4 + 0] = v.x; tile[kr][(tid & 15) * 4 + 1] = v.y;
        tile[kr][(tid & 15) * 4 + 2] = v.z; tile[kr][(tid & 15) * 4 + 3] = v.w;
    }
    __syncthreads();
    const int nr = tid >> 2, kc = (tid & 3) * 16;
    bf16x8 hi0, hi1, lo0, lo1;
    #pragma unroll
    for (int j = 0; j < 8; ++j) {
        float x = tile[kc + j][nr];
        __bf16 h = (__bf16)x; hi0[j] = h; lo0[j] = (__bf16)(x - (float)h);
        float y = tile[kc + 8 + j][nr];
        __bf16 g = (__bf16)y; hi1[j] = g; lo1[j] = (__bf16)(y - (float)g);
    }
    __bf16* row = Bp + (size_t)(n0 + nr) * 2048;
    *(bf16x8*)(row + k0 + kc)            = hi0;
    *(bf16x8*)(row + k0 + kc + 8)        = hi1;
    *(bf16x8*)(row + 1024 + k0 + kc)     = lo0;
    *(bf16x8*)(row + 1024 + k0 + kc + 8) = lo1;
}

// standalone Wz split for small-ws fallback (writes d_in[4] after prep)
__global__ __launch_bounds__(256) void split_bt1(
    const float* __restrict__ W, __bf16* __restrict__ Bp)
{
    __shared__ float tile[64][65];
    const int tid = (int)threadIdx.x;
    const int k0 = blockIdx.y * 64, n0 = blockIdx.x * 64;
    #pragma unroll
    for (int p = 0; p < 4; ++p) {
        int kr = p * 16 + (tid >> 4);
        float4 v = *(const float4*)(W + (size_t)(k0 + kr) * 1024 + n0 + (tid & 15) * 4);
        tile[kr][(tid & 15) * 4 + 0] = v.x; tile[kr][(tid & 15) * 4 + 1] = v.y;
        tile[kr][(tid & 15) * 4 + 2] = v.z; tile[kr][(tid & 15) * 4 + 3] = v.w;
    }
    __syncthreads();
    const int nr = tid >> 2, kc = (tid & 3) * 16;
    bf16x8 hi0, hi1, lo0, lo1;
    #pragma unroll
    for (int j = 0; j < 8; ++j) {
        float x = tile[kc + j][nr];
        __bf16 h = (__bf16)x; hi0[j] = h; lo0[j] = (__bf16)(x - (float)h);
        float y = tile[kc + 8 + j][nr];
        __bf16 g = (__bf16)y; hi1[j] = g; lo1[j] = (__bf16)(y - (float)g);
    }
    __bf16* row = Bp + (size_t)(n0 + nr) * 2048;
    *(bf16x8*)(row + k0 + kc)            = hi0;
    *(bf16x8*)(row + k0 + kc + 8)        = hi1;
    *(bf16x8*)(row + 1024 + k0 + kc)     = lo0;
    *(bf16x8*)(row + 1024 + k0 + kc + 8) = lo1;
}

// ------------------------------------------------------------------
// gemm_split: projections. Grid (n:8, m:32, z:3).
// fuseQK: z in {0,1} remapped M-blocking + normalize/gather -> Qp/Kp;
// z==2 transposeOut -> PTv. Tail: fill-units 640..4095 (attn heads 5..31).
// ------------------------------------------------------------------
__global__ __launch_bounds__(256) void gemm_split(
    const __bf16* __restrict__ Ap0, size_t aSlice, int aStride,
    const __bf16* __restrict__ Bp0, size_t bSlice,
    const float* __restrict__ b0, const float* __restrict__ b1,
    const float* __restrict__ b2, float* __restrict__ PTv,
    int chunksQK, int chunksV,
    __bf16* __restrict__ Qp, __bf16* __restrict__ Kp,
    float* __restrict__ AttnFill)
{
    const int z = blockIdx.z;
    const int nch = (z == 2) ? chunksV : chunksQK;
    const bool fuse = (z < 2);
    const __bf16* Ap = Ap0 + (size_t)z * aSlice;
    const __bf16* Bp = Bp0 + (size_t)z * bSlice;
    const float* bias = z == 0 ? b0 : (z == 1 ? b1 : b2);

    __shared__ __bf16 As[2 * 128 * 32];
    __shared__ __bf16 Bs[2 * 128 * 32];

    const int tid = (int)threadIdx.x;
    const int wave = tid >> 6, lane = tid & 63;
    const int quad = lane >> 4, tl = lane & 15;
    const int m0 = blockIdx.y * 128, n0 = blockIdx.x * 128;
    const int waveM = wave >> 1, waveN = wave & 1;

    floatx4 acc[4][4];
    #pragma unroll
    for (int i = 0; i < 4; ++i)
        #pragma unroll
        for (int j = 0; j < 4; ++j)
            acc[i][j] = (floatx4){0.f, 0.f, 0.f, 0.f};

    const int sRow  = (wave << 4) + (lane >> 2);
    const int sColB = (lane & 3) << 4;
    auto* AsL = (__attribute__((address_space(3))) char*)As;
    auto* BsL = (__attribute__((address_space(3))) char*)Bs;
    const int ldsOff = wave * 1024;

    // A global row for tile-row mrow (identity, or remapped for fused Q/K:
    // m = g'*64+u -> r = (u>>5)*2048 + by*64 + g'*32 + (u&31))
    size_t aRow[2];
    #pragma unroll
    for (int i = 0; i < 2; ++i) {
        const int mrow = i * 64 + sRow;
        if (fuse) {
            const int u = mrow & 63;
            aRow[i] = (size_t)((u >> 5) * 2048 + (m0 >> 1) + (mrow >> 6) * 32 + (u & 31));
        } else {
            aRow[i] = (size_t)(m0 + mrow);
        }
    }

    for (int k0 = 0; k0 < 1024; k0 += 32) {
        __syncthreads();
        #pragma unroll
        for (int i = 0; i < 2; ++i) {
            GLOAD_LDS16((const char*)(Ap + aRow[i] * aStride + k0) + sColB,
                        AsL + i * 4096 + ldsOff);
            GLOAD_LDS16((const char*)(Bp + (size_t)(n0 + i*64 + sRow) * 2048 + k0) + sColB,
                        BsL + i * 4096 + ldsOff);
            if (nch > 1) {
                GLOAD_LDS16((const char*)(Ap + 1024 + aRow[i] * aStride + k0) + sColB,
                            AsL + 8192 + i * 4096 + ldsOff);
                GLOAD_LDS16((const char*)(Bp + 1024 + (size_t)(n0 + i*64 + sRow) * 2048 + k0) + sColB,
                            BsL + 8192 + i * 4096 + ldsOff);
            }
        }
        __syncthreads();

        bf16x8 ah[4], bh[4], al[4], bl[4];
        #pragma unroll
        for (int mt = 0; mt < 4; ++mt)
            ah[mt] = *(const bf16x8*)(As + (waveM*64 + mt*16 + tl) * 32 + quad * 8);
        #pragma unroll
        for (int nt = 0; nt < 4; ++nt)
            bh[nt] = *(const bf16x8*)(Bs + (waveN*64 + nt*16 + tl) * 32 + quad * 8);
        #pragma unroll
        for (int mt = 0; mt < 4; ++mt)
            #pragma unroll
            for (int nt = 0; nt < 4; ++nt)
                acc[mt][nt] = __builtin_amdgcn_mfma_f32_16x16x32_bf16(
                    ah[mt], bh[nt], acc[mt][nt], 0, 0, 0);
        if (nch > 1) {
            #pragma unroll
            for (int mt = 0; mt < 4; ++mt)
                al[mt] = *(const bf16x8*)(As + 4096 + (waveM*64 + mt*16 + tl) * 32 + quad * 8);
            #pragma unroll
            for (int mt = 0; mt < 4; ++mt)
                #pragma unroll
                for (int nt = 0; nt < 4; ++nt)
                    acc[mt][nt] = __builtin_amdgcn_mfma_f32_16x16x32_bf16(
                        al[mt], bh[nt], acc[mt][nt], 0, 0, 0);
        }
        if (nch > 2) {
            #pragma unroll
            for (int nt = 0; nt < 4; ++nt)
                bl[nt] = *(const bf16x8*)(Bs + 4096 + (waveN*64 + nt*16 + tl) * 32 + quad * 8);
            #pragma unroll
            for (int mt = 0; mt < 4; ++mt)
                #pragma unroll
                for (int nt = 0; nt < 4; ++nt)
                    acc[mt][nt] = __builtin_amdgcn_mfma_f32_16x16x32_bf16(
                        ah[mt], bl[nt], acc[mt][nt], 0, 0, 0);
        }
    }

    if (fuse) {
        // normalize + head-gather epilogue. Group = 64 elements (fixed e,
        // u in [0,64)) all held by waves with this waveM.
        __bf16* Outp = (z == 0) ? Qp : Kp;
        const int g = ((m0 >> 7) << 1) + waveM;       // sp & 63
        #pragma unroll
        for (int nt = 0; nt < 4; ++nt) {
            const int e = n0 + waveN * 64 + nt * 16 + tl;
            const float bb = bias[e];
            float vals[16];
            float ss = 0.f;
            #pragma unroll
            for (int mt = 0; mt < 4; ++mt)
                #pragma unroll
                for (int reg = 0; reg < 4; ++reg) {
                    float vv = acc[mt][nt][reg] + bb;
                    vals[mt * 4 + reg] = vv;
                    ss += vv * vv;
                }
            ss += __shfl_xor(ss, 16);
            ss += __shfl_xor(ss, 32);
            const float inv = 1.0f / sqrtf(ss);
            const int head = ((e >> 9) << 4) + ((e >> 5) & 15);
            const int sp = ((e & 31) << 6) + g;
            __bf16* row = Outp + ((size_t)head * 2048 + sp) * 128;
            // d quadruple (d0..d0+3) <- vals{(mt,r0),(mt+2,r0),(mt,r0+1),
            // (mt+2,r0+1)}: bf16x4 8B stores (value-identical to scalars).
            #pragma unroll
            for (int mt = 0; mt < 2; ++mt)
                #pragma unroll
                for (int r0 = 0; r0 < 4; r0 += 2) {
                    const int d0 = (mt * 16 + quad * 4 + r0) * 2;
                    float v0 = vals[mt * 4 + r0] * inv;
                    float v1 = vals[(mt + 2) * 4 + r0] * inv;
                    float v2 = vals[mt * 4 + r0 + 1] * inv;
                    float v3 = vals[(mt + 2) * 4 + r0 + 1] * inv;
                    bf16x4 hv, lo4;
                    hv[0] = (__bf16)v0; lo4[0] = (__bf16)(v0 - (float)hv[0]);
                    hv[1] = (__bf16)v1; lo4[1] = (__bf16)(v1 - (float)hv[1]);
                    hv[2] = (__bf16)v2; lo4[2] = (__bf16)(v2 - (float)hv[2]);
                    hv[3] = (__bf16)v3; lo4[3] = (__bf16)(v3 - (float)hv[3]);
                    *(bf16x4*)(row + d0) = hv;
                    *(bf16x4*)(row + 64 + d0) = lo4;
                }
        }
    } else {
        // transposed PT output for v_transpose (z==2)
        #pragma unroll
        for (int nt = 0; nt < 4; ++nt) {
            const int e = n0 + waveN * 64 + nt * 16 + tl;
            const float bb = bias[e];
            #pragma unroll
            for (int mt = 0; mt < 4; ++mt) {
                floatx4 v = acc[mt][nt] + bb;
                *(floatx4*)(PTv + (size_t)e * 4096 + m0 + waveM * 64 + mt * 16 + quad * 4) = v;
            }
        }
    }

    // tail: attn upper-triangle zero-fill, heads 5..31 (units 640..4095).
    {
        const int L = (int)blockIdx.x + (int)blockIdx.y * 8 + z * 256; // 0..767
        for (int u = 640 + L; u < 4096; u += 768)
            fill_unit(AttnFill, u, tid);
    }
}

// ------------------------------------------------------------------
// gemm_out64 (r14): out-GEMM, 64x128 tiles, grid (8,64) = 2 blocks/CU.
// Tail: fill-units 0..127 (attn head 0; PTv dead, attn already done).
// ------------------------------------------------------------------
__global__ __launch_bounds__(256) void gemm_out64(
    const __bf16* __restrict__ Ap, const __bf16* __restrict__ Bp,
    const float* __restrict__ bias, float* __restrict__ Out,
    float* __restrict__ AttnFill)
{
    __shared__ __bf16 As[64 * 32];
    __shared__ __bf16 Bs[128 * 32];

    const int tid = (int)threadIdx.x;
    const int wave = tid >> 6, lane = tid & 63;
    const int quad = lane >> 4, tl = lane & 15;
    const int m0 = blockIdx.y * 64, n0 = blockIdx.x * 128;
    const int wm = wave >> 1, wn = wave & 1;

    floatx4 acc[2][4];
    #pragma unroll
    for (int i = 0; i < 2; ++i)
        #pragma unroll
        for (int j = 0; j < 4; ++j)
            acc[i][j] = (floatx4){0.f, 0.f, 0.f, 0.f};

    const int sRow  = (wave << 4) + (lane >> 2);   // 0..63
    const int sColB = (lane & 3) << 4;
    auto* AsL = (__attribute__((address_space(3))) char*)As;
    auto* BsL = (__attribute__((address_space(3))) char*)Bs;
    const int ldsOff = wave * 1024;

    for (int k0 = 0; k0 < 1024; k0 += 32) {
        __syncthreads();
        GLOAD_LDS16((const char*)(Ap + (size_t)(m0 + sRow) * 1024 + k0) + sColB,
                    AsL + ldsOff);
        #pragma unroll
        for (int i = 0; i < 2; ++i)
            GLOAD_LDS16((const char*)(Bp + (size_t)(n0 + i*64 + sRow) * 2048 + k0) + sColB,
                        BsL + i * 4096 + ldsOff);
        __syncthreads();

        bf16x8 ah[2], bh[4];
        #pragma unroll
        for (int mt = 0; mt < 2; ++mt)
            ah[mt] = *(const bf16x8*)(As + (wm*32 + mt*16 + tl) * 32 + quad * 8);
        #pragma unroll
        for (int nt = 0; nt < 4; ++nt)
            bh[nt] = *(const bf16x8*)(Bs + (wn*64 + nt*16 + tl) * 32 + quad * 8);
        #pragma unroll
        for (int mt = 0; mt < 2; ++mt)
            #pragma unroll
            for (int nt = 0; nt < 4; ++nt)
                acc[mt][nt] = __builtin_amdgcn_mfma_f32_16x16x32_bf16(
                    ah[mt], bh[nt], acc[mt][nt], 0, 0, 0);
    }

    #pragma unroll
    for (int mt = 0; mt < 2; ++mt) {
        const int rbase = m0 + wm * 32 + mt * 16 + quad * 4;
        #pragma unroll
        for (int nt = 0; nt < 4; ++nt) {
            const int e = n0 + wn * 64 + nt * 16 + tl;
            const float bb = bias[e];
            #pragma unroll
            for (int reg = 0; reg < 4; ++reg)
                Out[(size_t)(rbase + reg) * 1024 + e] = acc[mt][nt][reg] + bb;
        }
    }

    const int L = (int)blockIdx.x + (int)blockIdx.y * 8;   // 0..511
    if (L < 128)
        fill_unit(AttnFill, L, tid);
}

// ------------------------------------------------------------------
// v_transpose: PTv[e][4096] -> Vt[head][d=64][2048] bf16 (hi only).
// Tail: fill-units 128..639 (attn heads 1..4; Ap/Bp dead by now).
// ------------------------------------------------------------------
__global__ __launch_bounds__(256) void v_transpose(
    const float* __restrict__ PTv, __bf16* __restrict__ Vt,
    float* __restrict__ AttnFill)
{
    const int t = (int)blockIdx.x;        // 0..1023
    const int tid = (int)threadIdx.x;
    const int st = t & 31, head = t >> 5;
    const int c = (head >> 4) * 512 + (head & 15) * 32 + st;
    const float* __restrict__ row = PTv + (size_t)c * 4096;

    __shared__ float tile[64][65];
    #pragma unroll
    for (int i = 0; i < 4; ++i) {
        int o = i * 1024 + tid * 4;
        float4 v4 = *(const float4*)(row + o);
        float vals[4] = {v4.x, v4.y, v4.z, v4.w};
        #pragma unroll
        for (int e = 0; e < 4; ++e) {
            int oo = o + e;
            int d  = ((oo & 2047) & 31) * 2 + (oo >> 11);
            int sl = (oo & 2047) >> 5;
            tile[sl][d] = vals[e];
        }
    }
    __syncthreads();

    const int d = tid >> 2, jb = (tid & 3) * 16;
    bf16x8 h0, h1;
    #pragma unroll
    for (int j = 0; j < 8; ++j) {
        h0[j] = (__bf16)tile[jb + j][d];
        h1[j] = (__bf16)tile[jb + 8 + j][d];
    }
    size_t bh = ((size_t)head * 64 + d) * 2048 + st * 64 + jb;
    *(bf16x8*)(Vt + bh)     = h0;
    *(bf16x8*)(Vt + bh + 8) = h1;

    if (t < 512)
        fill_unit(AttnFill, 128 + t, tid);
}

// ------------------------------------------------------------------
// attn_mfma: block = (128 i-rows, head); 8 waves x 16 rows, 512 threads.
// QK^T: 3-chunk hi/lo. PV: single chunk. K/V staged via global_load_lds
// (XOR chunk swizzle) with DOUBLE BUFFERING. it-pairing: CU's two resident
// blocks sum to a constant 36 j-tiles; nt stores. No zero-fill here —
// upper triangle is pre/post-filled by the other kernels.
// ------------------------------------------------------------------
__global__ __launch_bounds__(512, 4) void attn_mfma(
    const __bf16* __restrict__ Qp, const __bf16* __restrict__ Kp,
    const __bf16* __restrict__ Vt, float* __restrict__ Attn,
    __bf16* __restrict__ Az)
{
    const int flat = (int)blockIdx.x;
    const int head = flat & 31;
    const int idx  = flat >> 5;                    // 0..15
    // pair heavy+light: CU gets blocks flat and flat+256 -> it and 15-it.
    const int it   = (idx < 8) ? (15 - idx) : (idx - 8);
    const int tid = (int)threadIdx.x;
    const int w = tid >> 6, lane = tid & 63;
    const int quad = lane >> 4, tl = lane & 15;
    const int t7 = tl & 7;
    const int i0 = it * 128;
    const int jtmax = 2 * it + 1;                  // always odd
    const int wrowMax = i0 + w * 16 + 15;
    const int wdiag   = (i0 + w * 16) >> 6;
    const int irowBase = w * 16 + quad * 4;

    const __bf16* __restrict__ Qh = Qp + ((size_t)head * 2048 + i0) * 128;
    const __bf16* __restrict__ Kh = Kp + (size_t)head * 2048 * 128;
    const __bf16* __restrict__ Vh = Vt + (size_t)head * 64 * 2048;
    float* __restrict__ Ah = Attn + (size_t)head * ((size_t)2048 * 2048);

    __shared__ __bf16 kb[2][64 * 128];   // K tile dbuf (2 x 16 KB)
    __shared__ __bf16 vt[2][64 * 64];    // V^T tile dbuf (2 x 8 KB)
    __shared__ __bf16 ps[8][16 * 72];    // wave-private P staging (18 KB)
    __bf16* psw = ps[w];
    auto* kbL = (__attribute__((address_space(3))) char*)&kb[0][0];
    auto* vtL = (__attribute__((address_space(3))) char*)&vt[0][0];

    // per-lane staging sources (swizzled)
    const char* kSrc[2];
    #pragma unroll
    for (int i = 0; i < 2; ++i) {
        int d  = i * 512 + tid;
        int rK = d >> 4, cK = (d & 15) ^ (rK & 7);
        kSrc[i] = (const char*)(Kh + (size_t)rK * 128) + cK * 16;
    }
    const char* vSrc;
    {
        int rV = tid >> 3, cV = (tid & 7) ^ (rV & 7);
        vSrc = (const char*)(Vh + (size_t)rV * 2048) + cV * 16;
    }
    const int ok0 = ((quad)      ^ t7) * 8;
    const int ok1 = ((quad + 4)  ^ t7) * 8;
    const int ok2 = ((quad + 8)  ^ t7) * 8;
    const int ok3 = ((quad + 12) ^ t7) * 8;

    // Q fragments direct from global (once per block)
    const __bf16* qrow = Qh + (size_t)(w * 16 + tl) * 128;
    bf16x8 qhi0 = *(const bf16x8*)(qrow + quad * 8);
    bf16x8 qhi1 = *(const bf16x8*)(qrow + 32 + quad * 8);
    bf16x8 qlo0 = *(const bf16x8*)(qrow + 64 + quad * 8);
    bf16x8 qlo1 = *(const bf16x8*)(qrow + 96 + quad * 8);

    float m[4], l[4];
    #pragma unroll
    for (int r = 0; r < 4; ++r) { m[r] = -3.0e38f; l[r] = 0.0f; }

    // ---------- pass 1: stats (K dbuf) ----------
    #pragma unroll
    for (int i = 0; i < 2; ++i)                       // prologue: jt=0 -> kb[0]
        GLOAD_LDS16(kSrc[i], kbL + i * 8192 + w * 1024);

    for (int jt = 0; jt <= jtmax; ++jt) {
        const int cur = jt & 1;
        __syncthreads();                              // publishes kb[cur]
        if (jt < jtmax) {                             // issue jt+1 -> kb[cur^1]
            #pragma unroll
            for (int i = 0; i < 2; ++i)
                GLOAD_LDS16(kSrc[i] + (size_t)(jt + 1) * 16384,
                            kbL + (cur ^ 1) * 16384 + i * 8192 + w * 1024);
        }
        if (jt * 64 > wrowMax) continue;              // fully masked (wave-uniform)

        const __bf16* kbuf = &kb[cur][0];
        const bool diag = (jt == wdiag);
        #pragma unroll
        for (int sub = 0; sub < 4; ++sub) {
            const __bf16* kr = kbuf + (sub * 16 + tl) * 128;
            bf16x8 khi0 = *(const bf16x8*)(kr + ok0);
            bf16x8 khi1 = *(const bf16x8*)(kr + ok1);
            bf16x8 klo0 = *(const bf16x8*)(kr + ok2);
            bf16x8 klo1 = *(const bf16x8*)(kr + ok3);
            floatx4 s = (floatx4){0.f, 0.f, 0.f, 0.f};
            s = __builtin_amdgcn_mfma_f32_16x16x32_bf16(qhi0, khi0, s, 0, 0, 0);
            s = __builtin_amdgcn_mfma_f32_16x16x32_bf16(qhi1, khi1, s, 0, 0, 0);
            s = __builtin_amdgcn_mfma_f32_16x16x32_bf16(qhi0, klo0, s, 0, 0, 0);
            s = __builtin_amdgcn_mfma_f32_16x16x32_bf16(qhi1, klo1, s, 0, 0, 0);
            s = __builtin_amdgcn_mfma_f32_16x16x32_bf16(qlo0, khi0, s, 0, 0, 0);
            s = __builtin_amdgcn_mfma_f32_16x16x32_bf16(qlo1, khi1, s, 0, 0, 0);
            const int col = jt * 64 + sub * 16 + tl;
            #pragma unroll
            for (int reg = 0; reg < 4; ++reg) {
                float lv = s[reg] * 1000.0f;
                if (diag && (col > i0 + irowBase + reg)) lv = -1.0e9f;
                float mn = fmaxf(m[reg], lv);
                l[reg] = l[reg] * __expf(m[reg] - mn) + __expf(lv - mn);
                m[reg] = mn;
            }
        }
    }

    // reduce stats across the 16 tl lanes
    #pragma unroll
    for (int reg = 0; reg < 4; ++reg) {
        #pragma unroll
        for (int mk = 8; mk >= 1; mk >>= 1) {
            float mo = __shfl_xor(m[reg], mk);
            float lo = __shfl_xor(l[reg], mk);
            float mn = fmaxf(m[reg], mo);
            l[reg] = l[reg] * __expf(m[reg] - mn) + lo * __expf(mo - mn);
            m[reg] = mn;
        }
    }
    float inv_l[4];
    #pragma unroll
    for (int reg = 0; reg < 4; ++reg) inv_l[reg] = 1.0f / l[reg];

    // ---------- pass 2: attn write + PV (K+V dbuf) ----------
    floatx4 zacc[4];
    #pragma unroll
    for (int t = 0; t < 4; ++t) zacc[t] = (floatx4){0.f, 0.f, 0.f, 0.f};

    // prologue: jt=0 -> kb[0], vt[0]. Safe: pass-1's last compute used
    // kb[jtmax&1] = kb[1] (jtmax odd), and all waves passed that barrier.
    #pragma unroll
    for (int i = 0; i < 2; ++i)
        GLOAD_LDS16(kSrc[i], kbL + i * 8192 + w * 1024);
    GLOAD_LDS16(vSrc, vtL + w * 1024);

    for (int jt = 0; jt <= jtmax; ++jt) {
        const int cur = jt & 1;
        __syncthreads();                              // publishes kb/vt[cur]
        if (jt < jtmax) {
            #pragma unroll
            for (int i = 0; i < 2; ++i)
                GLOAD_LDS16(kSrc[i] + (size_t)(jt + 1) * 16384,
                            kbL + (cur ^ 1) * 16384 + i * 8192 + w * 1024);
            GLOAD_LDS16(vSrc + (size_t)(jt + 1) * 128,
                        vtL + (cur ^ 1) * 8192 + w * 1024);
        }

        if (jt * 64 > wrowMax) continue;              // fully masked: pre-filled

        const __bf16* kbuf = &kb[cur][0];
        const __bf16* vbuf = &vt[cur][0];
        const bool diag = (jt == wdiag);
        #pragma unroll
        for (int sub = 0; sub < 4; ++sub) {
            const __bf16* kr = kbuf + (sub * 16 + tl) * 128;
            bf16x8 khi0 = *(const bf16x8*)(kr + ok0);
            bf16x8 khi1 = *(const bf16x8*)(kr + ok1);
            bf16x8 klo0 = *(const bf16x8*)(kr + ok2);
            bf16x8 klo1 = *(const bf16x8*)(kr + ok3);
            floatx4 s = (floatx4){0.f, 0.f, 0.f, 0.f};
            s = __builtin_amdgcn_mfma_f32_16x16x32_bf16(qhi0, khi0, s, 0, 0, 0);
            s = __builtin_amdgcn_mfma_f32_16x16x32_bf16(qhi1, khi1, s, 0, 0, 0);
            s = __builtin_amdgcn_mfma_f32_16x16x32_bf16(qhi0, klo0, s, 0, 0, 0);
            s = __builtin_amdgcn_mfma_f32_16x16x32_bf16(qhi1, klo1, s, 0, 0, 0);
            s = __builtin_amdgcn_mfma_f32_16x16x32_bf16(qlo0, khi0, s, 0, 0, 0);
            s = __builtin_amdgcn_mfma_f32_16x16x32_bf16(qlo1, khi1, s, 0, 0, 0);
            const int col = jt * 64 + sub * 16 + tl;
            #pragma unroll
            for (int reg = 0; reg < 4; ++reg) {
                float lv = s[reg] * 1000.0f;
                if (diag && (col > i0 + irowBase + reg)) lv = -1.0e9f;
                float p = __expf(lv - m[reg]) * inv_l[reg];
                psw[(quad * 4 + reg) * 72 + sub * 16 + tl] = (__bf16)p;
            }
        }
        // wave-private LDS: wait for writes (cross-lane reads next)
        __asm__ volatile("s_waitcnt lgkmcnt(0)" ::: "memory");

        // coalesced attn stores (non-temporal: never re-read on device)
        #pragma unroll
        for (int g = 0; g < 4; ++g) {
            bf16x4 pv = *(const bf16x4*)(psw + (g * 4 + quad) * 72 + tl * 4);
            floatx4 f = (floatx4){(float)pv[0], (float)pv[1],
                                  (float)pv[2], (float)pv[3]};
            nt_store4(Ah + (size_t)(i0 + w * 16 + g * 4 + quad) * 2048
                          + jt * 64 + tl * 4, f);
        }

        // P A-fragments, then PV MFMA (V hi only)
        bf16x8 p0 = *(const bf16x8*)(psw + tl * 72 + quad * 8);
        bf16x8 p1 = *(const bf16x8*)(psw + tl * 72 + 32 + quad * 8);
        #pragma unroll
        for (int t = 0; t < 4; ++t) {
            const __bf16* vh0 = vbuf + (t * 16 + tl) * 64;
            bf16x8 vhi0 = *(const bf16x8*)(vh0 + ok0);
            bf16x8 vhi1 = *(const bf16x8*)(vh0 + ok1);
            zacc[t] = __builtin_amdgcn_mfma_f32_16x16x32_bf16(p0, vhi0, zacc[t], 0, 0, 0);
            zacc[t] = __builtin_amdgcn_mfma_f32_16x16x32_bf16(p1, vhi1, zacc[t], 0, 0, 0);
        }
    }

    // epilogue: z -> Az bf16 (single chunk)
    const int b = head >> 4, h = head & 15;
    #pragma unroll
    for (int reg = 0; reg < 4; ++reg) {
        const size_t R = (size_t)b * 2048 + i0 + w * 16 + quad * 4 + reg;
        #pragma unroll
        for (int t = 0; t < 4; ++t)
            Az[R * 1024 + h * 64 + t * 16 + tl] = (__bf16)zacc[t][reg];
    }
}

// ------------------------------------------------------------------
extern "C" void kernel_launch(void* const* d_in, const int* in_sizes, int n_in,
                              void* d_out, int out_size, void* d_ws, size_t ws_size,
                              hipStream_t stream) {
    (void)in_sizes; (void)n_in; (void)out_size;
    const float* q  = (const float*)d_in[0];
    const float* k  = (const float*)d_in[1];
    const float* v  = (const float*)d_in[2];
    const float* Wq = (const float*)d_in[4];  const float* bq = (const float*)d_in[5];
    const float* Wk = (const float*)d_in[6];  const float* bk = (const float*)d_in[7];
    const float* Wv = (const float*)d_in[8];  const float* bv = (const float*)d_in[9];
    const float* Wz = (const float*)d_in[10]; const float* bz = (const float*)d_in[11];

    float* out0 = (float*)d_out;               // (2,2048,1024)
    float* attn = out0 + 4194304;              // (2,16,2048,2048) = 512 MB

    // Scratch in the attn region (head-aligned for fill safety):
    //  PTv: floats [0, 4194304)         = heads 0..1   (live until v_transpose)
    //  Ap0: floats [4194304, 16777216)  = heads 1..4   (live until proj done)
    //  Bp0: floats [16777216, 19922944) = heads 4..4.75
    float*  PTv = attn;
    __bf16* Ap0 = (__bf16*)(attn + 4194304);
    __bf16* Bp0 = (__bf16*)(attn + 16777216);

    // ws layout (big path): Qp 16MB | Kp 16MB | Vt 8MB | Az 8MB | Bpz 4MB
    __bf16 *Qp, *Kp, *Vtp, *Az, *Bpz;
    const bool bigWs = ws_size >= (size_t)54525952;   // 52 MB
    if (bigWs) {
        __bf16* ws = (__bf16*)d_ws;
        Qp = ws; Kp = ws + 8388608; Vtp = ws + 16777216; Az = ws + 20971520;
        Bpz = ws + 25165824;
    } else {
        Qp = (__bf16*)d_in[0]; Kp = (__bf16*)d_in[1]; Vtp = (__bf16*)d_in[2];
        Az = (__bf16*)d_ws;
        Bpz = (__bf16*)d_in[4];   // written by separate launch after prep
    }

    // prep: split_a (12288 blocks) + weight splits (256/slice)
    if (bigWs) {
        prep<<<dim3(12288 + 4 * 256), 256, 0, stream>>>(
            q, k, v, Ap0, Wq, Wk, Wv, Wz, Bp0, Bpz, 4);
    } else {
        prep<<<dim3(12288 + 3 * 256), 256, 0, stream>>>(
            q, k, v, Ap0, Wq, Wk, Wv, Wz, Bp0, nullptr, 3);
        split_bt1<<<dim3(16, 16), 256, 0, stream>>>(Wz, Bpz);
    }

    // projections: Q/K 3-chunk fused normalize+gather -> Qp/Kp;
    // V 1-chunk -> PTv. Tail-fills attn heads 5..31.
    gemm_split<<<dim3(8, 32, 3), 256, 0, stream>>>(
        Ap0, 4096ull*2048, 2048, Bp0, 1024ull*2048,
        bq, bk, bv, PTv, 3, 1,
        Qp, Kp, attn);

    // V transpose -> Vt. Tail-fills attn heads 1..4 (Ap/Bp dead).
    v_transpose<<<dim3(1024), 256, 0, stream>>>(PTv, Vtp, attn);

    attn_mfma<<<dim3(512), 512, 0, stream>>>(Qp, Kp, Vtp, attn, Az);

    // out-GEMM (2 blocks/CU). Tail-fills attn head 0 (PTv dead, attn done).
    gemm_out64<<<dim3(8, 64), 256, 0, stream>>>(Az, Bpz, bz, out0, attn);
}